// Round 2
// baseline (85.397 us; speedup 1.0000x reference)
//
#include <hip/hip_runtime.h>

#define NPART 4096
#define CT    16
#define ALPHA 2.8f
// R_ONSET=1.7, R_CUTOFF=2.0 -> r_o^2=2.89, r_c^2=4.0, (r_c^2-r_o^2)^3 = 1.367631
#define R_ON   1.7f
#define R_C2   4.0f
#define INV_DEN (1.0f / 1.367631f)
#define JC 64          // j-chunk per block
#define PPB 16         // particles per prep block

// ---------------------------------------------------------------------------
// Kernel 1: per-particle prep, LDS-staged.
//   w[i][d]  = sum_c ct[i,c] * 0.5*(E[i,c,d] + E[i,d,c])
//   maskv[i] = (sum_c ct[i,c] > 0) ? 1 : 0
//   posr[i]  = {x, y, z, radius}
// Each block owns 16 particles; their 16 KB of eps is staged into LDS with
// coalesced float4 loads (fixes the column-wise E[d*16+c] global reads).
// Row stride padded to 260 floats: keeps float4 alignment (1040 B) and
// rotates banks by 4 per particle (<=2-way conflicts, free).
// ---------------------------------------------------------------------------
__global__ __launch_bounds__(256) void prep_kernel(
        const float* __restrict__ pos,
        const float* __restrict__ ct,
        const float* __restrict__ eps,
        const float* __restrict__ rad,
        float* __restrict__ w,
        float* __restrict__ maskv,
        float4* __restrict__ posr,
        float* __restrict__ out) {
    __shared__ float S[PPB][260];
    __shared__ float CTs[PPB][16];
    const int tid = threadIdx.x;
    const int p0  = blockIdx.x * PPB;

    // stage eps: 16 particles x 256 floats = 1024 float4, coalesced
    const float4* e4 = (const float4*)(eps + p0 * (CT * CT));
#pragma unroll
    for (int q = tid; q < PPB * 64; q += 256) {
        float4 v = e4[q];
        int pp = q >> 6;           // particle within block
        int fo = (q & 63) << 2;    // float offset within its 256-float row
        *(float4*)&S[pp][fo] = v;
    }
    // stage celltype rows: 16 x 16 floats = 64 float4
    if (tid < 64) {
        int row = tid >> 2, qq = (tid & 3) << 2;
        *(float4*)&CTs[row][qq] = *(const float4*)(ct + (p0 + row) * CT + qq);
    }
    __syncthreads();

    const int p = tid >> 4;        // local particle
    const int d = tid & 15;
    float acc = 0.f;
#pragma unroll
    for (int c = 0; c < CT; ++c)
        acc += CTs[p][c] * 0.5f * (S[p][c * CT + d] + S[p][d * CT + c]);
    const int i = p0 + p;
    w[i * CT + d] = acc;

    if (d == 0) {
        float s = 0.f;
#pragma unroll
        for (int c = 0; c < CT; ++c) s += CTs[p][c];
        maskv[i] = (s > 0.f) ? 1.f : 0.f;
        posr[i] = make_float4(pos[3 * i], pos[3 * i + 1], pos[3 * i + 2], rad[i]);
    }
    if (tid == 0 && blockIdx.x == 0) *out = 0.f;
}

// ---------------------------------------------------------------------------
// Kernel 2: pair screen + rare-hit Morse energy.
// grid = (N/256 i-blocks, N/JC j-chunks). One i per thread; j loop is
// WAVE-UNIFORM -> posr[j], ct[j], w[j], maskv[j] all become scalar (SGPR)
// loads; the screen is ~8 VALU/pair with no LDS traffic. Hits (~0.05% of
// pairs) are processed inline under the exec mask.
// ---------------------------------------------------------------------------
__global__ __launch_bounds__(256) void pair_kernel(
        const float4* __restrict__ posr,
        const float* __restrict__ ct,
        const float* __restrict__ w,
        const float* __restrict__ maskv,
        float* __restrict__ out) {
    __shared__ float wsum_s[4];
    const int tid = threadIdx.x;
    const int i   = blockIdx.x * 256 + tid;
    const int j0  = blockIdx.y * JC;

    const float4 pi = posr[i];
    // i-side fragments in VGPRs (32 regs); 128 B/thread, L2-resident
    float cti[CT], wi[CT];
    const float4* ct4 = (const float4*)(ct + i * CT);
    const float4* w4  = (const float4*)(w + i * CT);
#pragma unroll
    for (int q = 0; q < 4; ++q) {
        float4 v = ct4[q];
        cti[4 * q] = v.x; cti[4 * q + 1] = v.y; cti[4 * q + 2] = v.z; cti[4 * q + 3] = v.w;
        float4 u = w4[q];
        wi[4 * q] = u.x; wi[4 * q + 1] = u.y; wi[4 * q + 2] = u.z; wi[4 * q + 3] = u.w;
    }

    float acc = 0.f;
#pragma unroll 4
    for (int j = j0; j < j0 + JC; ++j) {
        float4 pj = posr[j];               // wave-uniform -> s_load
        float dx = pi.x - pj.x, dy = pi.y - pj.y, dz = pi.z - pj.z;
        float r2 = dx * dx + dy * dy + dz * dz;
        if (r2 < R_C2 && j != i) {         // ~0.05% of pairs
            float dr = sqrtf(r2);
            float cut;
            if (dr < R_ON) {
                cut = 1.f;
            } else {
                float t1 = R_C2 - r2;
                cut = t1 * t1 * (2.f * r2 - 4.67f) * INV_DEN;
            }
            const float* ctj = ct + j * CT;   // uniform -> scalar loads
            const float* wj  = w + j * CT;
            float a = 0.f, b = 0.f;
#pragma unroll
            for (int c = 0; c < CT; ++c) {
                a += wi[c] * ctj[c];
                b += cti[c] * wj[c];
            }
            float bb   = 0.5f * (a + b);
            float epsv = maskv[j] * (5.f * __builtin_amdgcn_rcpf(1.f + __expf(-bb)) + 0.3f);
            float sigma = pi.w + pj.w;
            float u = 1.f - __expf(-ALPHA * (dr - sigma));
            acc += epsv * (u * u - 1.f) * cut;
        }
    }

    // wave(64) shuffle reduce -> LDS across 4 waves -> one atomic per block
#pragma unroll
    for (int off = 32; off; off >>= 1) acc += __shfl_down(acc, off, 64);
    int lane = tid & 63, wv = tid >> 6;
    if (lane == 0) wsum_s[wv] = acc;
    __syncthreads();
    if (tid == 0) atomicAdd(out, 0.5f * (wsum_s[0] + wsum_s[1] + wsum_s[2] + wsum_s[3]));
}

extern "C" void kernel_launch(void* const* d_in, const int* in_sizes, int n_in,
                              void* d_out, int out_size, void* d_ws, size_t ws_size,
                              hipStream_t stream) {
    const float* pos = (const float*)d_in[0];   // (N,3)
    const float* ct  = (const float*)d_in[1];   // (N,16)
    const float* eps = (const float*)d_in[2];   // (N,256)
    const float* rad = (const float*)d_in[3];   // (N,1)
    float* out = (float*)d_out;

    char* ws = (char*)d_ws;
    float*  w     = (float*)ws;                    // 4096*16*4 = 256 KB
    float4* posr  = (float4*)(ws + 256 * 1024);    // 4096*16  =  64 KB
    float*  maskv = (float*)(ws + 320 * 1024);     // 4096*4   =  16 KB

    prep_kernel<<<NPART / PPB, 256, 0, stream>>>(pos, ct, eps, rad, w, maskv, posr, out);
    dim3 grid(NPART / 256, NPART / JC);            // (16, 64) = 1024 blocks
    pair_kernel<<<grid, 256, 0, stream>>>(posr, ct, w, maskv, out);
}

// Round 3
// 77.273 us; speedup vs baseline: 1.1051x; 1.1051x over previous
//
#include <hip/hip_runtime.h>

#define NPART 4096
#define CT    16
#define ALPHA 2.8f
// R_ONSET=1.7, R_CUTOFF=2.0 -> r_o^2=2.89, r_c^2=4.0, (r_c^2-r_o^2)^3 = 1.11^3 = 1.367631
#define R_ON   1.7f
#define R_C2   4.0f
#define INV_DEN (1.0f / 1.367631f)
#define PPB    16      // particles per prep block
#define NCELL1 20      // cells per axis (BOX/RC = 40/2)
#define NCELLS (NCELL1 * NCELL1 * NCELL1)
#define CAP    16      // slots per cell (lambda=0.512 -> P(overflow) ~ 1e-20)

// ---------------------------------------------------------------------------
// Kernel 1: per-particle prep + cell binning (LDS-staged eps contraction).
//   w[i][d]  = sum_c ct[i,c] * 0.5*(E[i,c,d] + E[i,d,c])
//   maskv[i] = (sum_c ct[i,c] > 0) ? 1 : 0
//   posr[i]  = {x, y, z, radius}
//   bin i into its 2.0-edge cell (cellcnt pre-zeroed by memset)
// ---------------------------------------------------------------------------
__global__ __launch_bounds__(256) void prep_kernel(
        const float* __restrict__ pos,
        const float* __restrict__ ct,
        const float* __restrict__ eps,
        const float* __restrict__ rad,
        float* __restrict__ w,
        float* __restrict__ maskv,
        float4* __restrict__ posr,
        int* __restrict__ cellcnt,
        int* __restrict__ cellslot,
        float* __restrict__ out) {
    __shared__ float S[PPB][260];   // stride 260: float4-aligned, bank-rotated
    __shared__ float CTs[PPB][16];
    const int tid = threadIdx.x;
    const int p0  = blockIdx.x * PPB;

    // stage eps: 16 particles x 256 floats = 1024 float4, coalesced
    const float4* e4 = (const float4*)(eps + p0 * (CT * CT));
#pragma unroll
    for (int q = tid; q < PPB * 64; q += 256) {
        float4 v = e4[q];
        int pp = q >> 6;
        int fo = (q & 63) << 2;
        *(float4*)&S[pp][fo] = v;
    }
    if (tid < 64) {
        int row = tid >> 2, qq = (tid & 3) << 2;
        *(float4*)&CTs[row][qq] = *(const float4*)(ct + (p0 + row) * CT + qq);
    }
    __syncthreads();

    const int p = tid >> 4;
    const int d = tid & 15;
    float acc = 0.f;
#pragma unroll
    for (int c = 0; c < CT; ++c)
        acc += CTs[p][c] * 0.5f * (S[p][c * CT + d] + S[p][d * CT + c]);
    const int i = p0 + p;
    w[i * CT + d] = acc;

    if (d == 0) {
        float s = 0.f;
#pragma unroll
        for (int c = 0; c < CT; ++c) s += CTs[p][c];
        maskv[i] = (s > 0.f) ? 1.f : 0.f;
        float px = pos[3 * i], py = pos[3 * i + 1], pz = pos[3 * i + 2];
        posr[i] = make_float4(px, py, pz, rad[i]);
        int cx = min(NCELL1 - 1, (int)(px * 0.5f));
        int cy = min(NCELL1 - 1, (int)(py * 0.5f));
        int cz = min(NCELL1 - 1, (int)(pz * 0.5f));
        int cell = (cz * NCELL1 + cy) * NCELL1 + cx;
        int slot = atomicAdd(&cellcnt[cell], 1);
        if (slot < CAP) cellslot[cell * CAP + slot] = i;
    }
    if (tid == 0 && blockIdx.x == 0) *out = 0.f;
}

// ---------------------------------------------------------------------------
// Kernel 2: cell-list neighbor evaluation.
// Thread t -> (particle i = t>>5, neighbor-cell index c = t&31, active c<27).
// Each thread probes ONE of i's 27 neighbor cells (~0.5 occupants avg),
// evaluating the Morse energy for the ~2 hits/particle. 512 blocks x 256.
// ---------------------------------------------------------------------------
__global__ __launch_bounds__(256) void pair_kernel(
        const float4* __restrict__ posr,
        const float* __restrict__ ct,
        const float* __restrict__ w,
        const float* __restrict__ maskv,
        const int* __restrict__ cellcnt,
        const int* __restrict__ cellslot,
        float* __restrict__ out) {
    __shared__ float wsum_s[4];
    const int tid = threadIdx.x;
    const int t   = blockIdx.x * 256 + tid;
    const int i   = t >> 5;
    const int c   = t & 31;

    float acc = 0.f;
    if (c < 27) {
        const float4 pi = posr[i];
        int cx = min(NCELL1 - 1, (int)(pi.x * 0.5f));
        int cy = min(NCELL1 - 1, (int)(pi.y * 0.5f));
        int cz = min(NCELL1 - 1, (int)(pi.z * 0.5f));
        int nx = cx + (c % 3) - 1;
        int ny = cy + ((c / 3) % 3) - 1;
        int nz = cz + (c / 9) - 1;
        if (nx >= 0 && nx < NCELL1 && ny >= 0 && ny < NCELL1 &&
            nz >= 0 && nz < NCELL1) {
            int cell = (nz * NCELL1 + ny) * NCELL1 + nx;
            int cnt = min(cellcnt[cell], CAP);
            for (int k = 0; k < cnt; ++k) {
                int j = cellslot[cell * CAP + k];
                if (j == i) continue;
                float4 pj = posr[j];
                float dx = pi.x - pj.x, dy = pi.y - pj.y, dz = pi.z - pj.z;
                float r2 = dx * dx + dy * dy + dz * dz;
                if (r2 < R_C2) {
                    float dr = sqrtf(r2 > 0.f ? r2 : 1.f);  // ref safe-sqrt
                    float cut;
                    if (dr < R_ON) {
                        cut = 1.f;
                    } else {
                        float t1 = R_C2 - r2;
                        cut = t1 * t1 * (2.f * r2 - 4.67f) * INV_DEN;
                    }
                    const float4* cti4 = (const float4*)(ct + i * CT);
                    const float4* wi4  = (const float4*)(w + i * CT);
                    const float4* ctj4 = (const float4*)(ct + j * CT);
                    const float4* wj4  = (const float4*)(w + j * CT);
                    float a = 0.f, b = 0.f;
#pragma unroll
                    for (int q = 0; q < 4; ++q) {
                        float4 wiv = wi4[q], cjv = ctj4[q];
                        float4 civ = cti4[q], wjv = wj4[q];
                        a += wiv.x * cjv.x + wiv.y * cjv.y + wiv.z * cjv.z + wiv.w * cjv.w;
                        b += civ.x * wjv.x + civ.y * wjv.y + civ.z * wjv.z + civ.w * wjv.w;
                    }
                    float bb   = 0.5f * (a + b);
                    float epsv = maskv[j] * (5.f / (1.f + __expf(-bb)) + 0.3f);
                    float sigma = pi.w + pj.w;
                    float u = 1.f - __expf(-ALPHA * (dr - sigma));
                    acc += epsv * (u * u - 1.f) * cut;
                }
            }
        }
    }

    // wave(64) shuffle reduce -> LDS across 4 waves -> one atomic per block
#pragma unroll
    for (int off = 32; off; off >>= 1) acc += __shfl_down(acc, off, 64);
    int lane = tid & 63, wv = tid >> 6;
    if (lane == 0) wsum_s[wv] = acc;
    __syncthreads();
    if (tid == 0) atomicAdd(out, 0.5f * (wsum_s[0] + wsum_s[1] + wsum_s[2] + wsum_s[3]));
}

extern "C" void kernel_launch(void* const* d_in, const int* in_sizes, int n_in,
                              void* d_out, int out_size, void* d_ws, size_t ws_size,
                              hipStream_t stream) {
    const float* pos = (const float*)d_in[0];   // (N,3)
    const float* ct  = (const float*)d_in[1];   // (N,16)
    const float* eps = (const float*)d_in[2];   // (N,256)
    const float* rad = (const float*)d_in[3];   // (N,1)
    float* out = (float*)d_out;

    char* ws = (char*)d_ws;
    float*  w        = (float*)ws;                     // 256 KB
    float4* posr     = (float4*)(ws + 256 * 1024);     //  64 KB
    float*  maskv    = (float*)(ws + 320 * 1024);      //  16 KB
    int*    cellcnt  = (int*)(ws + 336 * 1024);        //  32 KB (8000 ints)
    int*    cellslot = (int*)(ws + 368 * 1024);        // 512 KB (8000*16 ints)

    hipMemsetAsync(cellcnt, 0, NCELLS * sizeof(int), stream);
    prep_kernel<<<NPART / PPB, 256, 0, stream>>>(pos, ct, eps, rad, w, maskv,
                                                 posr, cellcnt, cellslot, out);
    pair_kernel<<<NPART * 32 / 256, 256, 0, stream>>>(posr, ct, w, maskv,
                                                      cellcnt, cellslot, out);
}